// Round 3
// baseline (2832.712 us; speedup 1.0000x reference)
//
#include <hip/hip_runtime.h>
#include <stdint.h>

// Show-Attend-Tell forward, MI355X. B=128, P=196, E=2048, H=512, V=10000, T=20.
// R2: fused attn(hU+e+softmax+ctx), fused gates+LSTM (gate-interleaved WcT),
// batched out-GEMM over all 20 steps, 128x128-tile GEMM for the 2 big GEMMs.

typedef unsigned short u16;
typedef unsigned int u32;
typedef __attribute__((ext_vector_type(8))) short bf16x8;
typedef __attribute__((ext_vector_type(4))) float f32x4;

__device__ __forceinline__ float bf2f(u16 u) { return __uint_as_float(((u32)u) << 16); }
__device__ __forceinline__ u16 f2bf(float f) {
  u32 x = __float_as_uint(f);
  u32 r = x + 0x7fffu + ((x >> 16) & 1u);
  return (u16)(r >> 16);
}
__device__ __forceinline__ float tanh_f(float x) {
  x = fminf(15.f, fmaxf(-15.f, x));
  float e = __expf(2.f * x);
  return 1.f - 2.f * __builtin_amdgcn_rcpf(e + 1.f);
}
__device__ __forceinline__ float sigm_f(float x) {
  x = fminf(30.f, fmaxf(-30.f, x));
  return __builtin_amdgcn_rcpf(1.f + __expf(-x));
}

// ---- conversion: f32 -> bf16, 8 elems/thread, exact cover -------------------
__global__ __launch_bounds__(256) void k_f32_to_bf16(const float* __restrict__ in,
                                                     u16* __restrict__ out) {
  size_t i = ((size_t)blockIdx.x * 256 + threadIdx.x) * 8;
  float4 v0 = *(const float4*)(in + i);
  float4 v1 = *(const float4*)(in + i + 4);
  union { u16 u[8]; uint4 v; } r;
  r.u[0] = f2bf(v0.x); r.u[1] = f2bf(v0.y); r.u[2] = f2bf(v0.z); r.u[3] = f2bf(v0.w);
  r.u[4] = f2bf(v1.x); r.u[5] = f2bf(v1.y); r.u[6] = f2bf(v1.z); r.u[7] = f2bf(v1.w);
  *(uint4*)(out + i) = r.v;
}

// ---- mean over P (196) of imgb -> avgb bf16 ---------------------------------
__global__ __launch_bounds__(256) void k_avg(const u16* __restrict__ imgb,
                                             u16* __restrict__ avgb) {
  int b = blockIdx.y;
  int c0 = blockIdx.x * 512 + threadIdx.x * 2;
  const u32* p0 = (const u32*)(imgb + (size_t)b * 196 * 2048 + c0);
  float s0 = 0.f, s1 = 0.f;
  for (int p = 0; p < 196; ++p) {
    u32 v = p0[(size_t)p * 1024];
    s0 += bf2f((u16)(v & 0xffff));
    s1 += bf2f((u16)(v >> 16));
  }
  const float inv = 1.f / 196.f;
  u32 o = ((u32)f2bf(s1 * inv) << 16) | (u32)f2bf(s0 * inv);
  *(u32*)(avgb + (size_t)b * 2048 + c0) = o;
}

// ---- transpose f32[R,C] -> bf16[Cpad, R]; PERM applies LSTM gate interleave -
template <bool PERM>
__global__ __launch_bounds__(256) void k_transpose_bf16(const float* __restrict__ in,
                                                        int R, int C, int Cpad,
                                                        u16* __restrict__ out, int out_ld) {
  __shared__ float tile[32][33];
  int c0 = blockIdx.x * 32, r0 = blockIdx.y * 32;
  int tx = threadIdx.x, ty = threadIdx.y;  // (32, 8)
#pragma unroll
  for (int i = 0; i < 32; i += 8) {
    int r = r0 + ty + i, c = c0 + tx;
    tile[ty + i][tx] = (r < R && c < C) ? in[(size_t)r * C + c] : 0.f;
  }
  __syncthreads();
#pragma unroll
  for (int i = 0; i < 32; i += 8) {
    int c = c0 + ty + i, r = r0 + tx;
    if (c < Cpad && r < R) {
      int co = PERM ? ((c & 511) * 4 + (c >> 9)) : c;
      out[(size_t)co * out_ld + r] = f2bf(tile[tx][ty + i]);
    }
  }
}

// ---- cbias[perm(n)] = sum_k emb[0,k]*Wih[k,n] + bih[n] + bhh[n] -------------
__global__ __launch_bounds__(256) void k_cbias(const float* __restrict__ emb,
                                               const float* __restrict__ Wih,
                                               const float* __restrict__ bih,
                                               const float* __restrict__ bhh,
                                               float* __restrict__ cb) {
  __shared__ float e0[512];
  int tid = threadIdx.x;
  for (int i = tid; i < 512; i += 256) e0[i] = emb[i];
  __syncthreads();
  int n = blockIdx.x * 256 + tid;
  float s = bih[n] + bhh[n];
  for (int k = 0; k < 512; ++k) s += e0[k] * Wih[(size_t)k * 2048 + n];
  cb[(n & 511) * 4 + (n >> 9)] = s;
}

// ---- 64x64-tile MFMA GEMM with fused epilogues ------------------------------
enum { EPI_TANH_H = 0, EPI_TANH_C, EPI_GATE, EPI_LSTM };

template <int EPI>
__global__ __launch_bounds__(256) void k_gemm64(
    const u16* __restrict__ A, const u16* __restrict__ BT, int K, int Ntiles,
    const float* __restrict__ bias, float* __restrict__ outF,
    u16* __restrict__ outB, u16* __restrict__ outB2, u16* __restrict__ outB3,
    const float* __restrict__ ctx, int tstep) {
  __shared__ __align__(16) u16 Asm[64 * 72];
  __shared__ __align__(16) u16 Bsm[64 * 72];
  int bid = blockIdx.x;
  int mt = bid / Ntiles, nt = bid % Ntiles;
  long m0 = (long)mt * 64, n0 = (long)nt * 64;
  int tid = threadIdx.x, lane = tid & 63, w = tid >> 6;
  int srow = tid >> 3, schk = tid & 7;
  f32x4 acc[4] = {};
  const u16* Ap0 = A + (m0 + srow) * K + schk * 8;
  const u16* Ap1 = A + (m0 + srow + 32) * K + schk * 8;
  const u16* Bp0 = BT + (n0 + srow) * K + schk * 8;
  const u16* Bp1 = BT + (n0 + srow + 32) * K + schk * 8;
  u16* Aw0 = Asm + srow * 72 + schk * 8;
  u16* Aw1 = Asm + (srow + 32) * 72 + schk * 8;
  u16* Bw0 = Bsm + srow * 72 + schk * 8;
  u16* Bw1 = Bsm + (srow + 32) * 72 + schk * 8;
  const u16* Ar = Asm + (w * 16 + (lane & 15)) * 72 + (lane >> 4) * 8;
  const u16* Br = Bsm + (lane & 15) * 72 + (lane >> 4) * 8;
  for (int k0 = 0; k0 < K; k0 += 64) {
    uint4 a0 = *(const uint4*)(Ap0 + k0);
    uint4 a1 = *(const uint4*)(Ap1 + k0);
    uint4 b0 = *(const uint4*)(Bp0 + k0);
    uint4 b1 = *(const uint4*)(Bp1 + k0);
    __syncthreads();
    *(uint4*)Aw0 = a0;
    *(uint4*)Aw1 = a1;
    *(uint4*)Bw0 = b0;
    *(uint4*)Bw1 = b1;
    __syncthreads();
#pragma unroll
    for (int kk = 0; kk < 2; ++kk) {
      bf16x8 af = *(const bf16x8*)(Ar + kk * 32);
#pragma unroll
      for (int sn = 0; sn < 4; ++sn) {
        bf16x8 bfr = *(const bf16x8*)(Br + sn * 16 * 72 + kk * 32);
        acc[sn] = __builtin_amdgcn_mfma_f32_16x16x32_bf16(af, bfr, acc[sn], 0, 0, 0);
      }
    }
  }
  int cb = lane & 15, rb = (lane >> 4) * 4;
  if constexpr (EPI == EPI_LSTM) {
    // gates tile [64 b][64 n'] where n' = ch*4+gate (i,f,g,o interleaved)
    __shared__ float gtile[64][68];
#pragma unroll
    for (int sn = 0; sn < 4; ++sn)
#pragma unroll
      for (int r = 0; r < 4; ++r)
        gtile[w * 16 + rb + r][sn * 16 + cb] = acc[sn][r] + bias[n0 + sn * 16 + cb];
    __syncthreads();
#pragma unroll
    for (int i = 0; i < 4; ++i) {
      int idx = tid * 4 + i;
      int m = idx >> 4, chl = idx & 15;
      float iv = gtile[m][chl * 4 + 0];
      float fv = gtile[m][chl * 4 + 1];
      float gv = gtile[m][chl * 4 + 2];
      float ov = gtile[m][chl * 4 + 3];
      long bg = m0 + m;
      int ch = (int)(n0 >> 2) + chl;
      long ci = bg * 512 + ch;
      float cn = sigm_f(fv) * outF[ci] + sigm_f(iv) * tanh_f(gv);
      float h = sigm_f(ov) * tanh_f(cn);
      outF[ci] = cn;                              // c state
      u16 hv = f2bf(h);
      outB[ci] = hv;                              // hb
      outB2[bg * 2560 + 2048 + ch] = hv;          // next-step A buffer h part
      outB3[((long)tstep * 128 + bg) * 512 + ch] = hv;  // hAll
    }
  } else {
#pragma unroll
    for (int sn = 0; sn < 4; ++sn) {
#pragma unroll
      for (int r = 0; r < 4; ++r) {
        long m = m0 + w * 16 + rb + r;
        long n = n0 + sn * 16 + cb;
        float v = acc[sn][r];
        if (EPI == EPI_TANH_H) {
          u16 hv = f2bf(tanh_f(v + bias[n]));
          outB[m * 512 + n] = hv;
          outB2[m * 2560 + 2048 + n] = hv;
        } else if (EPI == EPI_TANH_C) {
          outF[m * 512 + n] = tanh_f(v + bias[n]);
        } else {  // EPI_GATE
          outB[m * 2560 + n] = f2bf(sigm_f(v + bias[n]) * ctx[m * 2048 + n]);
        }
      }
    }
  }
}

// ---- 128x128-tile MFMA GEMM (4 waves, 4x4 frags/wave, reg-staged, pad-72) ---
enum { EPI128_WS = 0, EPI128_OUT };

template <int EPI>
__global__ __launch_bounds__(256) void k_gemm128(
    const u16* __restrict__ A, const u16* __restrict__ BT, int K, int Ntiles,
    const float* __restrict__ bias, float* __restrict__ outF,
    u16* __restrict__ outB, int ncap) {
  __shared__ __align__(16) u16 Asm[128 * 72];
  __shared__ __align__(16) u16 Bsm[128 * 72];
  int bid = blockIdx.x;
  int mt = bid / Ntiles, nt = bid % Ntiles;
  long m0 = (long)mt * 128, n0 = (long)nt * 128;
  int tid = threadIdx.x, lane = tid & 63, w = tid >> 6;
  int wr = w >> 1, wc = w & 1;
  int srow = tid >> 3, schk = tid & 7;
  f32x4 acc[4][4] = {};
  const u16* Ap = A + (m0 + srow) * K + schk * 8;
  const u16* Bp = BT + (n0 + srow) * K + schk * 8;
  u16* Aw = Asm + srow * 72 + schk * 8;
  u16* Bw = Bsm + srow * 72 + schk * 8;
  const u16* Ar = Asm + (wr * 64 + (lane & 15)) * 72 + (lane >> 4) * 8;
  const u16* Br = Bsm + (wc * 64 + (lane & 15)) * 72 + (lane >> 4) * 8;
  for (int k0 = 0; k0 < K; k0 += 64) {
    uint4 a0 = *(const uint4*)(Ap + k0);
    uint4 a1 = *(const uint4*)(Ap + (size_t)32 * K + k0);
    uint4 a2 = *(const uint4*)(Ap + (size_t)64 * K + k0);
    uint4 a3 = *(const uint4*)(Ap + (size_t)96 * K + k0);
    uint4 b0 = *(const uint4*)(Bp + k0);
    uint4 b1 = *(const uint4*)(Bp + (size_t)32 * K + k0);
    uint4 b2 = *(const uint4*)(Bp + (size_t)64 * K + k0);
    uint4 b3 = *(const uint4*)(Bp + (size_t)96 * K + k0);
    __syncthreads();
    *(uint4*)Aw = a0;
    *(uint4*)(Aw + 32 * 72) = a1;
    *(uint4*)(Aw + 64 * 72) = a2;
    *(uint4*)(Aw + 96 * 72) = a3;
    *(uint4*)Bw = b0;
    *(uint4*)(Bw + 32 * 72) = b1;
    *(uint4*)(Bw + 64 * 72) = b2;
    *(uint4*)(Bw + 96 * 72) = b3;
    __syncthreads();
#pragma unroll
    for (int kk = 0; kk < 2; ++kk) {
      bf16x8 af[4], bfv[4];
#pragma unroll
      for (int i = 0; i < 4; ++i) {
        af[i] = *(const bf16x8*)(Ar + i * 16 * 72 + kk * 32);
        bfv[i] = *(const bf16x8*)(Br + i * 16 * 72 + kk * 32);
      }
#pragma unroll
      for (int sm = 0; sm < 4; ++sm)
#pragma unroll
        for (int sn = 0; sn < 4; ++sn)
          acc[sm][sn] = __builtin_amdgcn_mfma_f32_16x16x32_bf16(af[sm], bfv[sn],
                                                                acc[sm][sn], 0, 0, 0);
    }
  }
  int cb = lane & 15, rb = (lane >> 4) * 4;
#pragma unroll
  for (int sm = 0; sm < 4; ++sm) {
#pragma unroll
    for (int sn = 0; sn < 4; ++sn) {
#pragma unroll
      for (int r = 0; r < 4; ++r) {
        long m = m0 + wr * 64 + sm * 16 + rb + r;
        long n = n0 + wc * 64 + sn * 16 + cb;
        float v = acc[sm][sn][r];
        if (EPI == EPI128_WS) {
          outB[m * 512 + n] = f2bf(v + bias[n]);
        } else {  // EPI128_OUT: m = t*128+b -> preds[b, t, n]
          if (n < ncap) {
            long t = m >> 7, b = m & 127;
            outF[b * 200000 + t * 10000 + n] = v + bias[n];
          }
        }
      }
    }
  }
}

// ---- fused per-step attention: hU -> e -> softmax -> alpha store -> context -
__global__ __launch_bounds__(512) void k_attn_ctx(
    const u16* __restrict__ hb, const u16* __restrict__ UwB,
    const float* __restrict__ U_b, const float* __restrict__ v_w,
    const u16* __restrict__ WsB, const u16* __restrict__ imgb,
    float* __restrict__ ctx, float* __restrict__ alphas_t) {
  int b = blockIdx.x, tid = threadIdx.x, lane = tid & 63, w = tid >> 6;
  __shared__ float h_s[512], hu_s[512], v_s[512], al_s[200];
  h_s[tid] = bf2f(hb[b * 512 + tid]);
  v_s[tid] = v_w[tid];
  __syncthreads();
  // hU[n] = U_b[n] + sum_k h[k] * U[k,n]   (coalesced across n)
  {
    float s = U_b[tid];
    const u16* up = UwB + tid;
#pragma unroll 8
    for (int k = 0; k < 512; ++k) s += h_s[k] * bf2f(up[(size_t)k * 512]);
    hu_s[tid] = s;
  }
  __syncthreads();
  // e[p] = sum_h tanh(Ws[b,p,h] + hU[h]) * v[h]   (one wave per p, strided)
  for (int p = w; p < 196; p += 8) {
    uint4 pk = *(const uint4*)(WsB + ((size_t)b * 196 + p) * 512 + lane * 8);
    const u16* u = (const u16*)&pk;
    float e = 0.f;
#pragma unroll
    for (int j = 0; j < 8; ++j) {
      int hch = lane * 8 + j;
      e += tanh_f(bf2f(u[j]) + hu_s[hch]) * v_s[hch];
    }
#pragma unroll
    for (int off = 32; off; off >>= 1) e += __shfl_xor(e, off);
    if (lane == 0) al_s[p] = e;  // v_b cancels in softmax
  }
  __syncthreads();
  if (w == 0) {
    float mx = -1e30f;
    for (int q = lane; q < 196; q += 64) mx = fmaxf(mx, al_s[q]);
#pragma unroll
    for (int off = 32; off; off >>= 1) mx = fmaxf(mx, __shfl_xor(mx, off));
    float ssum = 0.f;
    for (int q = lane; q < 196; q += 64) {
      float ex = __expf(al_s[q] - mx);
      al_s[q] = ex;
      ssum += ex;
    }
#pragma unroll
    for (int off = 32; off; off >>= 1) ssum += __shfl_xor(ssum, off);
    float inv = 1.f / ssum;
    for (int q = lane; q < 196; q += 64) al_s[q] *= inv;
  }
  __syncthreads();
  if (tid < 196) alphas_t[(size_t)b * 3920 + tid] = al_s[tid];
  // context[b, :] = sum_p alpha[p] * img[b, p, :]  (4 channels per thread)
  const u32* ib = (const u32*)(imgb + (size_t)b * 196 * 2048) + tid;
  float a0 = 0.f, a1 = 0.f, a2 = 0.f, a3 = 0.f;
#pragma unroll 2
  for (int p = 0; p < 196; ++p) {
    float ap = al_s[p];
    u32 v0 = ib[(size_t)p * 1024];
    u32 v1 = ib[(size_t)p * 1024 + 512];
    a0 += ap * bf2f((u16)(v0 & 0xffff));
    a1 += ap * bf2f((u16)(v0 >> 16));
    a2 += ap * bf2f((u16)(v1 & 0xffff));
    a3 += ap * bf2f((u16)(v1 >> 16));
  }
  float* cp = ctx + (size_t)b * 2048;
  cp[tid * 2] = a0;
  cp[tid * 2 + 1] = a1;
  cp[1024 + tid * 2] = a2;
  cp[1024 + tid * 2 + 1] = a3;
}

extern "C" void kernel_launch(void* const* d_in, const int* in_sizes, int n_in,
                              void* d_out, int out_size, void* d_ws, size_t ws_size,
                              hipStream_t stream) {
  const float* img = (const float*)d_in[0];
  // d_in[1] captions: only defines static T=20; d_in[7] v_b: cancels in softmax
  const float* U_w = (const float*)d_in[2];
  const float* U_b = (const float*)d_in[3];
  const float* W_w = (const float*)d_in[4];
  const float* W_b = (const float*)d_in[5];
  const float* v_w = (const float*)d_in[6];
  const float* ih_w = (const float*)d_in[8];
  const float* ih_b = (const float*)d_in[9];
  const float* ic_w = (const float*)d_in[10];
  const float* ic_b = (const float*)d_in[11];
  const float* fb_w = (const float*)d_in[12];
  const float* fb_b = (const float*)d_in[13];
  const float* out_w = (const float*)d_in[14];
  const float* out_b = (const float*)d_in[15];
  const float* emb = (const float*)d_in[16];
  const float* Wih = (const float*)d_in[17];
  const float* Whh = (const float*)d_in[18];
  const float* bih = (const float*)d_in[19];
  const float* bhh = (const float*)d_in[20];
  float* preds = (float*)d_out;                    // [128,20,10000]
  float* alphas = (float*)d_out + 25600000;        // [128,20,196]

  char* ws = (char*)d_ws;
  size_t off = 0;
  auto alloc = [&](size_t bytes) {
    void* p = ws + off;
    off = (off + bytes + 255) & ~(size_t)255;
    return p;
  };
  u16* imgb = (u16*)alloc((size_t)128 * 196 * 2048 * 2);   // 102.8 MB
  u16* avgb = (u16*)alloc((size_t)128 * 2048 * 2);
  u16* WsB = (u16*)alloc((size_t)128 * 196 * 512 * 2);     // 25.7 MB
  u16* WwT = (u16*)alloc((size_t)512 * 2048 * 2);
  u16* UwB = (u16*)alloc((size_t)512 * 512 * 2);           // straight convert
  u16* ihT = (u16*)alloc((size_t)512 * 2048 * 2);
  u16* icT = (u16*)alloc((size_t)512 * 2048 * 2);
  u16* fbT = (u16*)alloc((size_t)2048 * 512 * 2);
  u16* WcT = (u16*)alloc((size_t)2048 * 2560 * 2);         // gate-interleaved
  u16* owT = (u16*)alloc((size_t)10112 * 512 * 2);         // zero-pad to 79 tiles
  float* cbias = (float*)alloc(2048 * 4);
  u16* hb = (u16*)alloc((size_t)128 * 512 * 2);
  float* cbuf = (float*)alloc((size_t)128 * 512 * 4);
  float* ctx = (float*)alloc((size_t)128 * 2048 * 4);
  u16* AbufA = (u16*)alloc((size_t)128 * 2560 * 2);
  u16* AbufB = (u16*)alloc((size_t)128 * 2560 * 2);
  u16* hAll = (u16*)alloc((size_t)2560 * 512 * 2);         // [t*128+b, 512]
  if (off > ws_size) return;
  (void)in_sizes; (void)n_in; (void)out_size;

  dim3 tb(32, 8);
  // --- one-time precompute ---
  k_f32_to_bf16<<<25088, 256, 0, stream>>>(img, imgb);
  k_f32_to_bf16<<<128, 256, 0, stream>>>(U_w, UwB);
  k_avg<<<dim3(4, 128), 256, 0, stream>>>(imgb, avgb);
  k_transpose_bf16<false><<<dim3(16, 64), tb, 0, stream>>>(W_w, 2048, 512, 512, WwT, 2048);
  k_transpose_bf16<false><<<dim3(16, 64), tb, 0, stream>>>(ih_w, 2048, 512, 512, ihT, 2048);
  k_transpose_bf16<false><<<dim3(16, 64), tb, 0, stream>>>(ic_w, 2048, 512, 512, icT, 2048);
  k_transpose_bf16<false><<<dim3(64, 16), tb, 0, stream>>>(fb_w, 512, 2048, 2048, fbT, 512);
  k_transpose_bf16<false><<<dim3(316, 16), tb, 0, stream>>>(out_w, 512, 10000, 10112, owT, 512);
  k_transpose_bf16<true><<<dim3(64, 64), tb, 0, stream>>>(Wih + 512 * 2048, 2048, 2048, 2048, WcT, 2560);
  k_transpose_bf16<true><<<dim3(64, 16), tb, 0, stream>>>(Whh, 512, 2048, 2048, WcT + 2048, 2560);
  k_cbias<<<8, 256, 0, stream>>>(emb, Wih, bih, bhh, cbias);
  // W_s = img @ W_w + W_b  (bf16 [25088, 512])
  k_gemm128<EPI128_WS><<<784, 256, 0, stream>>>(imgb, WwT, 2048, 4, W_b, nullptr, WsB, 0);
  // h0 / c0
  k_gemm64<EPI_TANH_H><<<16, 256, 0, stream>>>(avgb, ihT, 2048, 8, ih_b, nullptr, hb,
                                               AbufA, nullptr, nullptr, 0);
  k_gemm64<EPI_TANH_C><<<16, 256, 0, stream>>>(avgb, icT, 2048, 8, ic_b, cbuf, nullptr,
                                               nullptr, nullptr, nullptr, 0);

  for (int t = 0; t < 20; ++t) {
    u16* Acur = (t & 1) ? AbufB : AbufA;
    u16* Anxt = (t & 1) ? AbufA : AbufB;
    k_attn_ctx<<<128, 512, 0, stream>>>(hb, UwB, U_b, v_w, WsB, imgb, ctx,
                                        alphas + (size_t)t * 196);
    k_gemm64<EPI_GATE><<<64, 256, 0, stream>>>(hb, fbT, 512, 32, fb_b, nullptr, Acur,
                                               nullptr, nullptr, ctx, 0);
    k_gemm64<EPI_LSTM><<<64, 256, 0, stream>>>(Acur, WcT, 2560, 32, cbias, cbuf, hb,
                                               Anxt, hAll, nullptr, t);
  }
  // preds = hAll @ out_w + out_b  (one batched GEMM over all 20 steps)
  k_gemm128<EPI128_OUT><<<20 * 79, 256, 0, stream>>>(hAll, owT, 512, 79, out_b,
                                                     preds, nullptr, 10000);
}

// Round 5
// 2517.160 us; speedup vs baseline: 1.1254x; 1.1254x over previous
//
#include <hip/hip_runtime.h>
#include <stdint.h>

// Show-Attend-Tell forward, MI355X. B=128, P=196, E=2048, H=512, V=10000, T=20.
// R4: 2 kernels/step. A = heterogeneous {attention(b) | h@[fbT|WhhT] GEMM},
// B = on-the-fly (sigma(pre1L)*ctx) @ Wc2 + pre1R + cbias, fused LSTM epilogue.

typedef unsigned short u16;
typedef unsigned int u32;
typedef __attribute__((ext_vector_type(8))) short bf16x8;
typedef __attribute__((ext_vector_type(4))) float f32x4;

__device__ __forceinline__ float bf2f(u16 u) { return __uint_as_float(((u32)u) << 16); }
__device__ __forceinline__ u16 f2bf(float f) {
  u32 x = __float_as_uint(f);
  u32 r = x + 0x7fffu + ((x >> 16) & 1u);
  return (u16)(r >> 16);
}
__device__ __forceinline__ float tanh_f(float x) {
  x = fminf(15.f, fmaxf(-15.f, x));
  float e = __expf(2.f * x);
  return 1.f - 2.f * __builtin_amdgcn_rcpf(e + 1.f);
}
__device__ __forceinline__ float sigm_f(float x) {
  x = fminf(30.f, fmaxf(-30.f, x));
  return __builtin_amdgcn_rcpf(1.f + __expf(-x));
}

// ---- conversion: f32 -> bf16, 8 elems/thread ------------------------------
__global__ __launch_bounds__(256) void k_f32_to_bf16(const float* __restrict__ in,
                                                     u16* __restrict__ out) {
  size_t i = ((size_t)blockIdx.x * 256 + threadIdx.x) * 8;
  float4 v0 = *(const float4*)(in + i);
  float4 v1 = *(const float4*)(in + i + 4);
  union { u16 u[8]; uint4 v; } r;
  r.u[0] = f2bf(v0.x); r.u[1] = f2bf(v0.y); r.u[2] = f2bf(v0.z); r.u[3] = f2bf(v0.w);
  r.u[4] = f2bf(v1.x); r.u[5] = f2bf(v1.y); r.u[6] = f2bf(v1.z); r.u[7] = f2bf(v1.w);
  *(uint4*)(out + i) = r.v;
}

// ---- mean over P of imgb -> avgb bf16 -------------------------------------
__global__ __launch_bounds__(256) void k_avg(const u16* __restrict__ imgb,
                                             u16* __restrict__ avgb) {
  int b = blockIdx.y;
  int c0 = blockIdx.x * 512 + threadIdx.x * 2;
  const u32* p0 = (const u32*)(imgb + (size_t)b * 196 * 2048 + c0);
  float s0 = 0.f, s1 = 0.f;
  for (int p = 0; p < 196; ++p) {
    u32 v = p0[(size_t)p * 1024];
    s0 += bf2f((u16)(v & 0xffff));
    s1 += bf2f((u16)(v >> 16));
  }
  const float inv = 1.f / 196.f;
  u32 o = ((u32)f2bf(s1 * inv) << 16) | (u32)f2bf(s0 * inv);
  *(u32*)(avgb + (size_t)b * 2048 + c0) = o;
}

// ---- transpose f32[R,C] -> bf16[Cpad, R]; PERM = LSTM gate interleave -----
template <bool PERM>
__global__ __launch_bounds__(256) void k_transpose_bf16(const float* __restrict__ in,
                                                        int R, int C, int Cpad,
                                                        u16* __restrict__ out, int out_ld) {
  __shared__ float tile[32][33];
  int c0 = blockIdx.x * 32, r0 = blockIdx.y * 32;
  int tx = threadIdx.x, ty = threadIdx.y;  // (32, 8)
#pragma unroll
  for (int i = 0; i < 32; i += 8) {
    int r = r0 + ty + i, c = c0 + tx;
    tile[ty + i][tx] = (r < R && c < C) ? in[(size_t)r * C + c] : 0.f;
  }
  __syncthreads();
#pragma unroll
  for (int i = 0; i < 32; i += 8) {
    int c = c0 + ty + i, r = r0 + tx;
    if (c < Cpad && r < R) {
      int co = PERM ? ((c & 511) * 4 + (c >> 9)) : c;
      out[(size_t)co * out_ld + r] = f2bf(tile[tx][ty + i]);
    }
  }
}

// ---- cbias[perm(n)] = emb0 @ Wih + bih + bhh ------------------------------
__global__ __launch_bounds__(256) void k_cbias(const float* __restrict__ emb,
                                               const float* __restrict__ Wih,
                                               const float* __restrict__ bih,
                                               const float* __restrict__ bhh,
                                               float* __restrict__ cb) {
  __shared__ float e0[512];
  int tid = threadIdx.x;
  for (int i = tid; i < 512; i += 256) e0[i] = emb[i];
  __syncthreads();
  int n = blockIdx.x * 256 + tid;
  float s = bih[n] + bhh[n];
  for (int k = 0; k < 512; ++k) s += e0[k] * Wih[(size_t)k * 2048 + n];
  cb[(n & 511) * 4 + (n >> 9)] = s;
}

// ---- 64x64-tile MFMA GEMM (setup h0/c0 only) ------------------------------
enum { EPI_TANH_H = 0, EPI_TANH_C };

template <int EPI>
__global__ __launch_bounds__(256) void k_gemm64(
    const u16* __restrict__ A, const u16* __restrict__ BT, int K, int Ntiles,
    const float* __restrict__ bias, float* __restrict__ outF, u16* __restrict__ outB) {
  __shared__ __align__(16) u16 Asm[64 * 72];
  __shared__ __align__(16) u16 Bsm[64 * 72];
  int bid = blockIdx.x;
  int mt = bid / Ntiles, nt = bid % Ntiles;
  long m0 = (long)mt * 64, n0 = (long)nt * 64;
  int tid = threadIdx.x, lane = tid & 63, w = tid >> 6;
  int srow = tid >> 3, schk = tid & 7;
  f32x4 acc[4] = {};
  const u16* Ap0 = A + (m0 + srow) * K + schk * 8;
  const u16* Ap1 = A + (m0 + srow + 32) * K + schk * 8;
  const u16* Bp0 = BT + (n0 + srow) * K + schk * 8;
  const u16* Bp1 = BT + (n0 + srow + 32) * K + schk * 8;
  u16* Aw0 = Asm + srow * 72 + schk * 8;
  u16* Aw1 = Asm + (srow + 32) * 72 + schk * 8;
  u16* Bw0 = Bsm + srow * 72 + schk * 8;
  u16* Bw1 = Bsm + (srow + 32) * 72 + schk * 8;
  const u16* Ar = Asm + (w * 16 + (lane & 15)) * 72 + (lane >> 4) * 8;
  const u16* Br = Bsm + (lane & 15) * 72 + (lane >> 4) * 8;
  for (int k0 = 0; k0 < K; k0 += 64) {
    uint4 a0 = *(const uint4*)(Ap0 + k0);
    uint4 a1 = *(const uint4*)(Ap1 + k0);
    uint4 b0 = *(const uint4*)(Bp0 + k0);
    uint4 b1 = *(const uint4*)(Bp1 + k0);
    __syncthreads();
    *(uint4*)Aw0 = a0;
    *(uint4*)Aw1 = a1;
    *(uint4*)Bw0 = b0;
    *(uint4*)Bw1 = b1;
    __syncthreads();
#pragma unroll
    for (int kk = 0; kk < 2; ++kk) {
      bf16x8 af = *(const bf16x8*)(Ar + kk * 32);
#pragma unroll
      for (int sn = 0; sn < 4; ++sn) {
        bf16x8 bfr = *(const bf16x8*)(Br + sn * 16 * 72 + kk * 32);
        acc[sn] = __builtin_amdgcn_mfma_f32_16x16x32_bf16(af, bfr, acc[sn], 0, 0, 0);
      }
    }
  }
  int cb = lane & 15, rb = (lane >> 4) * 4;
#pragma unroll
  for (int sn = 0; sn < 4; ++sn) {
#pragma unroll
    for (int r = 0; r < 4; ++r) {
      long m = m0 + w * 16 + rb + r;
      long n = n0 + sn * 16 + cb;
      float v = acc[sn][r] + bias[n];
      if (EPI == EPI_TANH_H) outB[m * 512 + n] = f2bf(tanh_f(v));
      else outF[m * 512 + n] = tanh_f(v);
    }
  }
}

// ---- 128x128-tile MFMA GEMM (Ws + final out) ------------------------------
enum { EPI128_WS = 0, EPI128_OUT };

template <int EPI>
__global__ __launch_bounds__(256) void k_gemm128(
    const u16* __restrict__ A, const u16* __restrict__ BT, int K, int Ntiles,
    const float* __restrict__ bias, float* __restrict__ outF,
    u16* __restrict__ outB, int ncap) {
  __shared__ __align__(16) u16 Asm[128 * 72];
  __shared__ __align__(16) u16 Bsm[128 * 72];
  int bid = blockIdx.x;
  int mt = bid / Ntiles, nt = bid % Ntiles;
  long m0 = (long)mt * 128, n0 = (long)nt * 128;
  int tid = threadIdx.x, lane = tid & 63, w = tid >> 6;
  int wr = w >> 1, wc = w & 1;
  int srow = tid >> 3, schk = tid & 7;
  f32x4 acc[4][4] = {};
  const u16* Ap = A + (m0 + srow) * K + schk * 8;
  const u16* Bp = BT + (n0 + srow) * K + schk * 8;
  u16* Aw = Asm + srow * 72 + schk * 8;
  u16* Bw = Bsm + srow * 72 + schk * 8;
  const u16* Ar = Asm + (wr * 64 + (lane & 15)) * 72 + (lane >> 4) * 8;
  const u16* Br = Bsm + (wc * 64 + (lane & 15)) * 72 + (lane >> 4) * 8;
  for (int k0 = 0; k0 < K; k0 += 64) {
    uint4 a0 = *(const uint4*)(Ap + k0);
    uint4 a1 = *(const uint4*)(Ap + (size_t)32 * K + k0);
    uint4 a2 = *(const uint4*)(Ap + (size_t)64 * K + k0);
    uint4 a3 = *(const uint4*)(Ap + (size_t)96 * K + k0);
    uint4 b0 = *(const uint4*)(Bp + k0);
    uint4 b1 = *(const uint4*)(Bp + (size_t)32 * K + k0);
    uint4 b2 = *(const uint4*)(Bp + (size_t)64 * K + k0);
    uint4 b3 = *(const uint4*)(Bp + (size_t)96 * K + k0);
    __syncthreads();
    *(uint4*)Aw = a0;
    *(uint4*)(Aw + 32 * 72) = a1;
    *(uint4*)(Aw + 64 * 72) = a2;
    *(uint4*)(Aw + 96 * 72) = a3;
    *(uint4*)Bw = b0;
    *(uint4*)(Bw + 32 * 72) = b1;
    *(uint4*)(Bw + 64 * 72) = b2;
    *(uint4*)(Bw + 96 * 72) = b3;
    __syncthreads();
#pragma unroll
    for (int kk = 0; kk < 2; ++kk) {
      bf16x8 af[4], bfv[4];
#pragma unroll
      for (int i = 0; i < 4; ++i) {
        af[i] = *(const bf16x8*)(Ar + i * 16 * 72 + kk * 32);
        bfv[i] = *(const bf16x8*)(Br + i * 16 * 72 + kk * 32);
      }
#pragma unroll
      for (int sm = 0; sm < 4; ++sm)
#pragma unroll
        for (int sn = 0; sn < 4; ++sn)
          acc[sm][sn] = __builtin_amdgcn_mfma_f32_16x16x32_bf16(af[sm], bfv[sn],
                                                                acc[sm][sn], 0, 0, 0);
    }
  }
  int cb = lane & 15, rb = (lane >> 4) * 4;
#pragma unroll
  for (int sm = 0; sm < 4; ++sm) {
#pragma unroll
    for (int sn = 0; sn < 4; ++sn) {
#pragma unroll
      for (int r = 0; r < 4; ++r) {
        long m = m0 + wr * 64 + sm * 16 + rb + r;
        long n = n0 + wc * 64 + sn * 16 + cb;
        float v = acc[sm][sn][r];
        if (EPI == EPI128_WS) {
          outB[m * 512 + n] = f2bf(v + bias[n]);
        } else {
          if (n < ncap) {
            long t = m >> 7, b = m & 127;
            outF[b * 200000 + t * 10000 + n] = v + bias[n];
          }
        }
      }
    }
  }
}

// ---- step kernel A: blocks 0..127 attention(b); 128..255 h@[fbT|WhhT] -----
__global__ __launch_bounds__(256) void k_stepA(
    const u16* __restrict__ hb, const u16* __restrict__ UwB,
    const float* __restrict__ U_b, const float* __restrict__ v_w,
    const u16* __restrict__ WsB, const u16* __restrict__ imgb,
    const u16* __restrict__ fWhT, const float* __restrict__ fb_b,
    float* __restrict__ ctx, float* __restrict__ pre1,
    float* __restrict__ alphas_t) {
  __shared__ __align__(16) char smem[46080];
  int bid = blockIdx.x, tid = threadIdx.x;
  int lane = tid & 63, w = tid >> 6;
  if (bid < 128) {
    int b = bid;
    float* h_s = (float*)smem;               // 512
    float* v_s = (float*)(smem + 2048);      // 512
    float* p4 = (float*)(smem + 4096);       // 4*512 (p4[0] -> hu after reduce)
    float* al_s = (float*)(smem + 12288);    // 256
    float* ctxp = (float*)(smem + 13312);    // 4*2048
    {
      u32 hv = *(const u32*)(hb + b * 512 + tid * 2);
      h_s[tid * 2] = bf2f((u16)(hv & 0xffff));
      h_s[tid * 2 + 1] = bf2f((u16)(hv >> 16));
      float2 vv = *(const float2*)(v_w + tid * 2);
      v_s[tid * 2] = vv.x;
      v_s[tid * 2 + 1] = vv.y;
    }
    __syncthreads();
    // hU: wave w covers k-slice [w*128, w*128+128); lane covers n = lane*8..+8
    {
      float acc[8] = {};
      const u16* up = UwB + (size_t)(w * 128) * 512 + lane * 8;
#pragma unroll 4
      for (int k = 0; k < 128; ++k) {
        float hk = h_s[w * 128 + k];
        uint4 uv = *(const uint4*)(up + (size_t)k * 512);
        const u16* uu = (const u16*)&uv;
#pragma unroll
        for (int j = 0; j < 8; ++j) acc[j] += hk * bf2f(uu[j]);
      }
      float* dst = p4 + w * 512 + lane * 8;
#pragma unroll
      for (int j = 0; j < 8; ++j) dst[j] = acc[j];
    }
    __syncthreads();
    {
      int n = tid * 2;
#pragma unroll
      for (int j = 0; j < 2; ++j) {
        float s = U_b[n + j] + p4[n + j] + p4[512 + n + j] + p4[1024 + n + j] +
                  p4[1536 + n + j];
        p4[n + j] = s;
      }
    }
    __syncthreads();
    const float* hu_s = p4;
    // e[p] = sum_h tanh(Ws + hU) * v
    for (int p = w; p < 196; p += 4) {
      uint4 pk = *(const uint4*)(WsB + ((size_t)b * 196 + p) * 512 + lane * 8);
      const u16* uu = (const u16*)&pk;
      float e = 0.f;
#pragma unroll
      for (int j = 0; j < 8; ++j) {
        int hch = lane * 8 + j;
        e += tanh_f(bf2f(uu[j]) + hu_s[hch]) * v_s[hch];
      }
#pragma unroll
      for (int off = 32; off; off >>= 1) e += __shfl_xor(e, off);
      if (lane == 0) al_s[p] = e;  // v_b cancels in softmax
    }
    __syncthreads();
    if (w == 0) {
      float mx = -1e30f;
      for (int q = lane; q < 196; q += 64) mx = fmaxf(mx, al_s[q]);
#pragma unroll
      for (int off = 32; off; off >>= 1) mx = fmaxf(mx, __shfl_xor(mx, off));
      float ssum = 0.f;
      for (int q = lane; q < 196; q += 64) {
        float ex = __expf(al_s[q] - mx);
        al_s[q] = ex;
        ssum += ex;
      }
#pragma unroll
      for (int off = 32; off; off >>= 1) ssum += __shfl_xor(ssum, off);
      float inv = 1.f / ssum;
      for (int q = lane; q < 196; q += 64) al_s[q] *= inv;
    }
    __syncthreads();
    if (tid < 196) alphas_t[(size_t)b * 3920 + tid] = al_s[tid];
    // ctx: wave w covers p-slice; lane covers 32 channels (lane*32..+32)
    {
      float a32[32] = {};
      const u16* ib = imgb + (size_t)b * 196 * 2048 + lane * 32;
      for (int p = w; p < 196; p += 4) {
        float ap = al_s[p];
        const uint4* rp = (const uint4*)(ib + (size_t)p * 2048);
#pragma unroll
        for (int q = 0; q < 4; ++q) {
          uint4 v = rp[q];
          const u16* uu = (const u16*)&v;
#pragma unroll
          for (int j = 0; j < 8; ++j) a32[q * 8 + j] += ap * bf2f(uu[j]);
        }
      }
      float* dst = ctxp + w * 2048 + lane * 32;
#pragma unroll
      for (int j = 0; j < 32; ++j) dst[j] = a32[j];
    }
    __syncthreads();
    {
      int c0 = tid * 8;
#pragma unroll
      for (int j = 0; j < 8; ++j) {
        int c = c0 + j;
        ctx[(size_t)b * 2048 + c] =
            ctxp[c] + ctxp[2048 + c] + ctxp[4096 + c] + ctxp[6144 + c];
      }
    }
  } else {
    // gemm1: pre1[128,4096] = h @ [fbT|WhhT]^T (+fb_b on left half)
    u16* Asm = (u16*)smem;            // 64*72
    u16* Bsm = (u16*)(smem + 9216);   // 64*72
    int g = bid - 128;
    int mt = g >> 6, nt = g & 63;
    long m0 = (long)mt * 64, n0 = (long)nt * 64;
    int srow = tid >> 3, schk = tid & 7;
    f32x4 acc[4] = {};
    const u16* Ap0 = hb + (m0 + srow) * 512 + schk * 8;
    const u16* Ap1 = hb + (m0 + srow + 32) * 512 + schk * 8;
    const u16* Bp0 = fWhT + (n0 + srow) * 512 + schk * 8;
    const u16* Bp1 = fWhT + (n0 + srow + 32) * 512 + schk * 8;
    u16* Aw0 = Asm + srow * 72 + schk * 8;
    u16* Aw1 = Asm + (srow + 32) * 72 + schk * 8;
    u16* Bw0 = Bsm + srow * 72 + schk * 8;
    u16* Bw1 = Bsm + (srow + 32) * 72 + schk * 8;
    const u16* Ar = Asm + (w * 16 + (lane & 15)) * 72 + (lane >> 4) * 8;
    const u16* Br = Bsm + (lane & 15) * 72 + (lane >> 4) * 8;
#pragma unroll 1
    for (int k0 = 0; k0 < 512; k0 += 64) {
      uint4 a0 = *(const uint4*)(Ap0 + k0);
      uint4 a1 = *(const uint4*)(Ap1 + k0);
      uint4 b0 = *(const uint4*)(Bp0 + k0);
      uint4 b1 = *(const uint4*)(Bp1 + k0);
      __syncthreads();
      *(uint4*)Aw0 = a0;
      *(uint4*)Aw1 = a1;
      *(uint4*)Bw0 = b0;
      *(uint4*)Bw1 = b1;
      __syncthreads();
#pragma unroll
      for (int kk = 0; kk < 2; ++kk) {
        bf16x8 af = *(const bf16x8*)(Ar + kk * 32);
#pragma unroll
        for (int sn = 0; sn < 4; ++sn) {
          bf16x8 bfr = *(const bf16x8*)(Br + sn * 16 * 72 + kk * 32);
          acc[sn] = __builtin_amdgcn_mfma_f32_16x16x32_bf16(af, bfr, acc[sn], 0, 0, 0);
        }
      }
    }
    int cb = lane & 15, rb = (lane >> 4) * 4;
#pragma unroll
    for (int sn = 0; sn < 4; ++sn) {
#pragma unroll
      for (int r = 0; r < 4; ++r) {
        long m = m0 + w * 16 + rb + r;
        long n = n0 + sn * 16 + cb;
        float v = acc[sn][r];
        if (n < 2048) v += fb_b[n];
        pre1[m * 4096 + n] = v;
      }
    }
  }
}

// ---- step kernel B: gates GEMM (A on-the-fly) + LSTM epilogue -------------
__global__ __launch_bounds__(256) void k_stepB(
    const float* __restrict__ pre1, const float* __restrict__ ctx,
    const u16* __restrict__ Wc2, const float* __restrict__ cbias,
    float* __restrict__ cbuf, u16* __restrict__ hb, u16* __restrict__ hAll,
    int tstep) {
  __shared__ __align__(16) u16 Asm[32 * 72];
  __shared__ __align__(16) u16 Bsm[64 * 72];
  __shared__ float gtile[32][68];
  int bid = blockIdx.x;
  int mt = bid >> 5, nt = bid & 31;
  int m0 = mt * 32, n0 = nt * 64;
  int tid = threadIdx.x, lane = tid & 63, w = tid >> 6;
  int arow = tid >> 3, achk = tid & 7;
  int brow = tid >> 2, bchk = (tid & 3) * 16;
  f32x4 acc0 = {}, acc1 = {};
  const float* pA = pre1 + (size_t)(m0 + arow) * 4096 + achk * 8;
  const float* pC = ctx + (size_t)(m0 + arow) * 2048 + achk * 8;
  const u16* pB = Wc2 + (size_t)(n0 + brow) * 2048 + bchk;
  u16* Aw = Asm + arow * 72 + achk * 8;
  u16* Bw = Bsm + brow * 72 + bchk;
  const u16* Ar = Asm + (lane & 15) * 72 + (lane >> 4) * 8;
  const u16* Br = Bsm + (w * 16 + (lane & 15)) * 72 + (lane >> 4) * 8;
  for (int k0 = 0; k0 < 2048; k0 += 64) {
    float4 g0 = *(const float4*)(pA + k0);
    float4 g1 = *(const float4*)(pA + k0 + 4);
    float4 c0 = *(const float4*)(pC + k0);
    float4 c1 = *(const float4*)(pC + k0 + 4);
    uint4 b0 = *(const uint4*)(pB + k0);
    uint4 b1 = *(const uint4*)(pB + k0 + 8);
    union { u16 u[8]; uint4 v; } av;
    av.u[0] = f2bf(sigm_f(g0.x) * c0.x);
    av.u[1] = f2bf(sigm_f(g0.y) * c0.y);
    av.u[2] = f2bf(sigm_f(g0.z) * c0.z);
    av.u[3] = f2bf(sigm_f(g0.w) * c0.w);
    av.u[4] = f2bf(sigm_f(g1.x) * c1.x);
    av.u[5] = f2bf(sigm_f(g1.y) * c1.y);
    av.u[6] = f2bf(sigm_f(g1.z) * c1.z);
    av.u[7] = f2bf(sigm_f(g1.w) * c1.w);
    __syncthreads();
    *(uint4*)Aw = av.v;
    *(uint4*)Bw = b0;
    *(uint4*)(Bw + 8) = b1;
    __syncthreads();
#pragma unroll
    for (int kk = 0; kk < 2; ++kk) {
      bf16x8 a0 = *(const bf16x8*)(Ar + kk * 32);
      bf16x8 a1 = *(const bf16x8*)(Ar + 16 * 72 + kk * 32);
      bf16x8 bb = *(const bf16x8*)(Br + kk * 32);
      acc0 = __builtin_amdgcn_mfma_f32_16x16x32_bf16(a0, bb, acc0, 0, 0, 0);
      acc1 = __builtin_amdgcn_mfma_f32_16x16x32_bf16(a1, bb, acc1, 0, 0, 0);
    }
  }
  int cbb = lane & 15, rb = (lane >> 4) * 4;
#pragma unroll
  for (int s = 0; s < 2; ++s) {
#pragma unroll
    for (int r = 0; r < 4; ++r) {
      int m = s * 16 + rb + r;
      int nl = w * 16 + cbb;
      float v = (s ? acc1[r] : acc0[r]) +
                pre1[(size_t)(m0 + m) * 4096 + 2048 + n0 + nl] + cbias[n0 + nl];
      gtile[m][nl] = v;
    }
  }
  __syncthreads();
#pragma unroll
  for (int i = 0; i < 2; ++i) {
    int idx = tid * 2 + i;
    int m = idx >> 4, chl = idx & 15;
    float iv = gtile[m][chl * 4 + 0];
    float fv = gtile[m][chl * 4 + 1];
    float gv = gtile[m][chl * 4 + 2];
    float ov = gtile[m][chl * 4 + 3];
    long bg = m0 + m;
    int ch = (n0 >> 2) + chl;
    long ci = bg * 512 + ch;
    float cn = sigm_f(fv) * cbuf[ci] + sigm_f(iv) * tanh_f(gv);
    float h = sigm_f(ov) * tanh_f(cn);
    cbuf[ci] = cn;
    u16 hv = f2bf(h);
    hb[ci] = hv;
    hAll[((size_t)tstep * 128 + bg) * 512 + ch] = hv;
  }
}

extern "C" void kernel_launch(void* const* d_in, const int* in_sizes, int n_in,
                              void* d_out, int out_size, void* d_ws, size_t ws_size,
                              hipStream_t stream) {
  const float* img = (const float*)d_in[0];
  // d_in[1] captions: static T=20; d_in[7] v_b: cancels in softmax
  const float* U_w = (const float*)d_in[2];
  const float* U_b = (const float*)d_in[3];
  const float* W_w = (const float*)d_in[4];
  const float* W_b = (const float*)d_in[5];
  const float* v_w = (const float*)d_in[6];
  const float* ih_w = (const float*)d_in[8];
  const float* ih_b = (const float*)d_in[9];
  const float* ic_w = (const float*)d_in[10];
  const float* ic_b = (const float*)d_in[11];
  const float* fb_w = (const float*)d_in[12];
  const float* fb_b = (const float*)d_in[13];
  const float* out_w = (const float*)d_in[14];
  const float* out_b = (const float*)d_in[15];
  const float* emb = (const float*)d_in[16];
  const float* Wih = (const float*)d_in[17];
  const float* Whh = (const float*)d_in[18];
  const float* bih = (const float*)d_in[19];
  const float* bhh = (const float*)d_in[20];
  float* preds = (float*)d_out;              // [128,20,10000]
  float* alphas = (float*)d_out + 25600000;  // [128,20,196]

  char* ws = (char*)d_ws;
  size_t off = 0;
  auto alloc = [&](size_t bytes) {
    void* p = ws + off;
    off = (off + bytes + 255) & ~(size_t)255;
    return p;
  };
  u16* imgb = (u16*)alloc((size_t)128 * 196 * 2048 * 2);
  u16* avgb = (u16*)alloc((size_t)128 * 2048 * 2);
  u16* WsB = (u16*)alloc((size_t)128 * 196 * 512 * 2);
  u16* WwT = (u16*)alloc((size_t)512 * 2048 * 2);
  u16* UwB = (u16*)alloc((size_t)512 * 512 * 2);
  u16* ihT = (u16*)alloc((size_t)512 * 2048 * 2);
  u16* icT = (u16*)alloc((size_t)512 * 2048 * 2);
  u16* fWhT = (u16*)alloc((size_t)4096 * 512 * 2);   // [fbT | permuted WhhT]
  u16* Wc2 = (u16*)alloc((size_t)2048 * 2048 * 2);   // permuted Wih_ctx^T
  u16* owT = (u16*)alloc((size_t)10112 * 512 * 2);
  float* cbias = (float*)alloc(2048 * 4);
  u16* hb = (u16*)alloc((size_t)128 * 512 * 2);
  float* cbuf = (float*)alloc((size_t)128 * 512 * 4);
  float* ctx = (float*)alloc((size_t)128 * 2048 * 4);
  float* pre1 = (float*)alloc((size_t)128 * 4096 * 4);
  u16* hAll = (u16*)alloc((size_t)2560 * 512 * 2);
  if (off > ws_size) return;
  (void)in_sizes; (void)n_in; (void)out_size;

  dim3 tb(32, 8);
  // --- one-time precompute ---
  k_f32_to_bf16<<<25088, 256, 0, stream>>>(img, imgb);
  k_f32_to_bf16<<<128, 256, 0, stream>>>(U_w, UwB);
  k_avg<<<dim3(4, 128), 256, 0, stream>>>(imgb, avgb);
  k_transpose_bf16<false><<<dim3(16, 64), tb, 0, stream>>>(W_w, 2048, 512, 512, WwT, 2048);
  k_transpose_bf16<false><<<dim3(16, 64), tb, 0, stream>>>(ih_w, 2048, 512, 512, ihT, 2048);
  k_transpose_bf16<false><<<dim3(16, 64), tb, 0, stream>>>(ic_w, 2048, 512, 512, icT, 2048);
  k_transpose_bf16<false><<<dim3(64, 16), tb, 0, stream>>>(fb_w, 512, 2048, 2048, fWhT, 512);
  k_transpose_bf16<true><<<dim3(64, 16), tb, 0, stream>>>(Whh, 512, 2048, 2048,
                                                          fWhT + (size_t)2048 * 512, 512);
  k_transpose_bf16<true><<<dim3(64, 64), tb, 0, stream>>>(Wih + 512 * 2048, 2048, 2048,
                                                          2048, Wc2, 2048);
  k_transpose_bf16<false><<<dim3(316, 16), tb, 0, stream>>>(out_w, 512, 10000, 10112, owT, 512);
  k_cbias<<<8, 256, 0, stream>>>(emb, Wih, bih, bhh, cbias);
  // W_s = img @ W_w + W_b
  k_gemm128<EPI128_WS><<<784, 256, 0, stream>>>(imgb, WwT, 2048, 4, W_b, nullptr, WsB, 0);
  // h0 / c0
  k_gemm64<EPI_TANH_H><<<16, 256, 0, stream>>>(avgb, ihT, 2048, 8, ih_b, nullptr, hb);
  k_gemm64<EPI_TANH_C><<<16, 256, 0, stream>>>(avgb, icT, 2048, 8, ic_b, cbuf, nullptr);

  for (int t = 0; t < 20; ++t) {
    k_stepA<<<256, 256, 0, stream>>>(hb, UwB, U_b, v_w, WsB, imgb, fWhT, fb_b, ctx,
                                     pre1, alphas + (size_t)t * 196);
    k_stepB<<<128, 256, 0, stream>>>(pre1, ctx, Wc2, cbias, cbuf, hb, hAll, t);
  }
  // preds = hAll @ out_w + out_b
  k_gemm128<EPI128_OUT><<<20 * 79, 256, 0, stream>>>(hAll, owT, 512, 79, out_b,
                                                     preds, nullptr, 10000);
}